// Round 8
// baseline (181.583 us; speedup 1.0000x reference)
//
#include <hip/hip_runtime.h>

typedef __bf16 bf16;
typedef __bf16 bf16x4 __attribute__((ext_vector_type(4)));
typedef __bf16 bf16x8 __attribute__((ext_vector_type(8)));
typedef float f32x4 __attribute__((ext_vector_type(4)));

#define MFMA16(a, b, c) __builtin_amdgcn_mfma_f32_16x16x32_bf16((a), (b), (c), 0, 0, 0)

// global -> LDS DMA, 16B per lane; LDS dest is wave-uniform base + lane*16.
#define GLD16(gp, lp)                                                              \
  __builtin_amdgcn_global_load_lds(                                                \
      (const __attribute__((address_space(1))) unsigned int*)(unsigned long long)(gp), \
      (__attribute__((address_space(3))) unsigned int*)(unsigned long long)(lp), 16, 0, 0)

// B=256, T=320, C=1024, H=64;  M = B*T = 81920
// ws (bf16): Wt [3][64][1024] | Qw [81920][64] | Kw [81920][64] | Vt [256][64][320]

// ---------------- Kernel 0: W -> Wt (bf16, [mat][h][k]) ----------------
__global__ __launch_bounds__(256) void wtrans_kernel(
    const float* __restrict__ Wk, const float* __restrict__ Wq,
    const float* __restrict__ Wv, bf16* __restrict__ Wt) {
  __shared__ bf16 tile[64][65];
  const int mat = blockIdx.x >> 4;
  const int kt = (blockIdx.x & 15) << 6;
  const float* __restrict__ W = (mat == 0) ? Wk : ((mat == 1) ? Wq : Wv);
  const int tid = threadIdx.x;
#pragma unroll
  for (int j = 0; j < 16; ++j) {
    const int i = tid + 256 * j;
    const int k = i >> 6, h = i & 63;
    tile[h][k] = (bf16)W[(kt + k) * 64 + h];
  }
  __syncthreads();
#pragma unroll
  for (int j = 0; j < 16; ++j) {
    const int i = tid + 256 * j;
    const int h = i >> 6, k = i & 63;
    Wt[mat * 65536 + h * 1024 + kt + k] = tile[h][k];
  }
}

// ---------------- Kernel 1: fused QKV projection (frozen, round-5 version) ----------------
__global__ __launch_bounds__(256) void qkv_kernel(
    const float* __restrict__ x, const bf16* __restrict__ Wt,
    bf16* __restrict__ Qw, bf16* __restrict__ Kw, bf16* __restrict__ Vt) {
  __shared__ float xs3[3][64][64];  // 48 KB
  const int tid = threadIdx.x;
  const int w = tid >> 6, l = tid & 63;
  const int lr = l & 15, lg = l >> 4;
  const int m0 = blockIdx.x * 64;

  f32x4 acc[4][3];
#pragma unroll
  for (int mf = 0; mf < 4; ++mf)
#pragma unroll
    for (int nf = 0; nf < 3; ++nf) acc[mf][nf] = (f32x4)0.0f;

  const char* gb0;
  const char* gb1;
  const char* gb2;
  const char* gb3;
  {
    const int rr = l >> 4;
    const int cb = (l & 15) * 16;
    gb0 = (const char*)(x + (size_t)(m0 + 16 * w + 0 + rr) * 1024) + (cb ^ (((0 + rr) & 7) << 4));
    gb1 = (const char*)(x + (size_t)(m0 + 16 * w + 4 + rr) * 1024) + (cb ^ (((4 + rr) & 7) << 4));
    gb2 = (const char*)(x + (size_t)(m0 + 16 * w + 8 + rr) * 1024) + (cb ^ (((0 + rr) & 7) << 4));
    gb3 = (const char*)(x + (size_t)(m0 + 16 * w + 12 + rr) * 1024) + (cb ^ (((4 + rr) & 7) << 4));
  }

  bf16x8 wf[3][2];
  auto loadw = [&](int kt) {
#pragma unroll
    for (int nf = 0; nf < 3; ++nf) {
      const int colg = w * 48 + nf * 16 + lr;
      const bf16* p = Wt + (colg >> 6) * 65536 + (colg & 63) * 1024 + kt + lg * 8;
      wf[nf][0] = *(const bf16x8*)p;
      wf[nf][1] = *(const bf16x8*)(p + 32);
    }
  };
  auto dma = [&](int t) {
    char* lb = (char*)&xs3[t % 3][16 * w][0];
    const int ko = t * 256;
    GLD16(gb0 + ko, lb + 0 * 1024);
    GLD16(gb1 + ko, lb + 1 * 1024);
    GLD16(gb2 + ko, lb + 2 * 1024);
    GLD16(gb3 + ko, lb + 3 * 1024);
  };

  dma(0);
  dma(1);
  const int sw = (lr & 7) << 4;
#pragma unroll
  for (int t = 0; t < 16; ++t) {
    if (t < 15) {
      asm volatile("s_waitcnt vmcnt(4)" ::: "memory");
    } else {
      asm volatile("s_waitcnt vmcnt(0)" ::: "memory");
    }
    __builtin_amdgcn_sched_barrier(0);
    __builtin_amdgcn_s_barrier();
    __builtin_amdgcn_sched_barrier(0);
    loadw(t * 64);
    if (t < 14) dma(t + 2);
    const char* xb = (const char*)&xs3[t % 3][0][0];
#pragma unroll
    for (int mf = 0; mf < 4; ++mf) {
      const char* rp = xb + (mf * 16 + lr) * 256;
      const f32x4 f0 = *(const f32x4*)(rp + ((lg * 32 + 0) ^ sw));
      const f32x4 f1 = *(const f32x4*)(rp + ((lg * 32 + 16) ^ sw));
      const f32x4 f2 = *(const f32x4*)(rp + (128 + ((lg * 32 + 0) ^ sw)));
      const f32x4 f3 = *(const f32x4*)(rp + (128 + ((lg * 32 + 16) ^ sw)));
      bf16x8 a0, a1;
#pragma unroll
      for (int j = 0; j < 4; ++j) {
        a0[j] = (bf16)f0[j]; a0[4 + j] = (bf16)f1[j];
        a1[j] = (bf16)f2[j]; a1[4 + j] = (bf16)f3[j];
      }
#pragma unroll
      for (int nf = 0; nf < 3; ++nf) {
        acc[mf][nf] = MFMA16(a0, wf[nf][0], acc[mf][nf]);
        acc[mf][nf] = MFMA16(a1, wf[nf][1], acc[mf][nf]);
      }
    }
  }

#pragma unroll
  for (int mf = 0; mf < 4; ++mf) {
#pragma unroll
    for (int nf = 0; nf < 3; ++nf) {
      const int colg = w * 48 + nf * 16 + lr;
      const int mat = colg >> 6, h = colg & 63;
      const int mb = m0 + mf * 16 + lg * 4;
      if (mat == 2) {
        const int b = mb / 320, t = mb % 320;
        bf16x4 o;
#pragma unroll
        for (int r = 0; r < 4; ++r) o[r] = (bf16)acc[mf][nf][r];
        *(bf16x4*)(Vt + ((size_t)b * 64 + h) * 320 + t) = o;
      } else {
        bf16* __restrict__ dst = (mat == 0) ? Kw : Qw;
#pragma unroll
        for (int r = 0; r < 4; ++r) dst[(size_t)(mb + r) * 64 + h] = (bf16)acc[mf][nf][r];
      }
    }
  }
}

// ---------------- Kernel 2: causal attention (frozen, round-6 version) ----------------
template <int QT>
__device__ __forceinline__ void attn_impl(
    int b, const bf16* __restrict__ Qw, const bf16* __restrict__ Kw,
    const bf16* __restrict__ Vt, float* __restrict__ out,
    char* Ks, char* Vs, char* Ps) {
  constexpr int NT = QT + 1;  // 64-wide s-tiles
  const int tid = threadIdx.x;
  const int w = tid >> 6, l = tid & 63;
  const int lr = l & 15, lg = l >> 4;
  const int t0 = QT * 64 + w * 16;
  const int tq = t0 + lr;

  const bf16* qp = Qw + ((size_t)b * 320 + tq) * 64 + lg * 8;
  const bf16x8 bq0 = *(const bf16x8*)qp;
  const bf16x8 bq1 = *(const bf16x8*)(qp + 32);

  f32x4 acc[NT * 4];
#pragma unroll
  for (int i = 0; i < NT * 4; ++i) acc[i] = (f32x4)0.0f;

  bf16x8 kg0, kg1;
  const int krow = w * 16 + (l >> 2);
  const int kcb = (l & 3) * 16;
  const int ksw = (krow & 7) << 4;
  auto gloadK = [&](int st) {
    const bf16* src = Kw + ((size_t)b * 320 + st * 64 + krow) * 64 + (l & 3) * 8;
    kg0 = *(const bf16x8*)src;
    kg1 = *(const bf16x8*)(src + 32);
  };
  auto dswriteK = [&](int buf) {
    char* base = Ks + buf * 8192 + krow * 128;
    *(bf16x8*)(base + (kcb ^ ksw)) = kg0;
    *(bf16x8*)(base + ((kcb + 64) ^ ksw)) = kg1;
  };

  gloadK(0);
  dswriteK(0);
  asm volatile("s_waitcnt lgkmcnt(0)" ::: "memory");
  __builtin_amdgcn_s_barrier();

  const int asw = (lr & 7) << 4;
#pragma unroll
  for (int st = 0; st < NT; ++st) {
    if (st < QT) gloadK(st + 1);
    const char* kb = Ks + (st & 1) * 8192;
#pragma unroll
    for (int nf = 0; nf < 4; ++nf) {
      const char* rp = kb + (nf * 16 + lr) * 128;
      const bf16x8 a0 = *(const bf16x8*)(rp + ((lg * 16) ^ asw));
      const bf16x8 a1 = *(const bf16x8*)(rp + ((64 + lg * 16) ^ asw));
      acc[st * 4 + nf] = MFMA16(a0, bq0, acc[st * 4 + nf]);
      acc[st * 4 + nf] = MFMA16(a1, bq1, acc[st * 4 + nf]);
    }
    if (st < QT) {
      dswriteK((st + 1) & 1);
      asm volatile("s_waitcnt lgkmcnt(0)" ::: "memory");
      __builtin_amdgcn_s_barrier();
    }
  }

  uint2 vg[4];
  const int vrow = w * 16 + (l >> 4);
  auto gloadV = [&](int st) {
    const bf16* src = Vt + ((size_t)b * 64 + vrow) * 320 + st * 64 + (l & 15) * 4;
#pragma unroll
    for (int i = 0; i < 4; ++i) vg[i] = *(const uint2*)(src + i * 4 * 320);
  };
  auto dswriteV = [&](int buf) {
#pragma unroll
    for (int i = 0; i < 4; ++i) {
      const int hl = vrow + i * 4;
      *(uint2*)(Vs + buf * 8192 + hl * 128 + (((l & 15) * 8) ^ ((hl & 7) << 4))) = vg[i];
    }
  };
  gloadV(0);

  float mx = -1e30f;
#pragma unroll
  for (int st = 0; st < NT; ++st)
#pragma unroll
    for (int nf = 0; nf < 4; ++nf)
#pragma unroll
      for (int r = 0; r < 4; ++r) {
        const int sg = st * 64 + nf * 16 + lg * 4 + r;
        float v = acc[st * 4 + nf][r] * 0.03125f;
        v = (sg > tq) ? -1e30f : v;
        acc[st * 4 + nf][r] = v;
        mx = fmaxf(mx, v);
      }
  mx = fmaxf(mx, __shfl_xor(mx, 16));
  mx = fmaxf(mx, __shfl_xor(mx, 32));
  float sum = 0.f;
#pragma unroll
  for (int i = 0; i < NT * 4; ++i)
#pragma unroll
    for (int r = 0; r < 4; ++r) {
      const float p = __expf(acc[i][r] - mx);
      acc[i][r] = p;
      sum += p;
    }
  sum += __shfl_xor(sum, 16);
  sum += __shfl_xor(sum, 32);
  const float rinv = 1.0f / sum;

  dswriteV(0);
  asm volatile("s_waitcnt lgkmcnt(0)" ::: "memory");
  __builtin_amdgcn_s_barrier();

  char* Pw = Ps + w * 2048;
  f32x4 ao[4];
#pragma unroll
  for (int hf = 0; hf < 4; ++hf) ao[hf] = (f32x4)0.0f;

#pragma unroll
  for (int st = 0; st < NT; ++st) {
    if (st < QT) gloadV(st + 1);
#pragma unroll
    for (int nf = 0; nf < 4; ++nf) {
      bf16x4 o;
#pragma unroll
      for (int r = 0; r < 4; ++r) o[r] = (bf16)(acc[st * 4 + nf][r] * rinv);
      *(bf16x4*)(Pw + lr * 128 + ((nf * 32 + lg * 8) ^ asw)) = o;
    }
    const char* vb = Vs + (st & 1) * 8192;
#pragma unroll
    for (int ks = 0; ks < 2; ++ks) {
      const bf16x8 ap = *(const bf16x8*)(Pw + lr * 128 + ((ks * 64 + lg * 16) ^ asw));
#pragma unroll
      for (int hf = 0; hf < 4; ++hf) {
        const bf16x8 bv =
            *(const bf16x8*)(vb + (hf * 16 + lr) * 128 + ((ks * 64 + lg * 16) ^ asw));
        ao[hf] = MFMA16(ap, bv, ao[hf]);
      }
    }
    if (st < QT) {
      dswriteV((st + 1) & 1);
      asm volatile("s_waitcnt lgkmcnt(0)" ::: "memory");
      __builtin_amdgcn_s_barrier();
    }
  }

  const int rowb = t0 + lg * 4;
#pragma unroll
  for (int hf = 0; hf < 4; ++hf)
#pragma unroll
    for (int r = 0; r < 4; ++r)
      out[((size_t)b * 320 + rowb + r) * 64 + hf * 16 + lr] = ao[hf][r];
}

__global__ __launch_bounds__(256) void attn_kernel(
    const bf16* __restrict__ Qw, const bf16* __restrict__ Kw,
    const bf16* __restrict__ Vt, float* __restrict__ out) {
  __shared__ __align__(16) char Ks[2 * 8192];
  __shared__ __align__(16) char Vs[2 * 8192];
  __shared__ __align__(16) char Ps[4 * 2048];
  const int b = blockIdx.x;
  const int qt = 4 - blockIdx.y;  // heavy blocks dispatch first
  switch (qt) {
    case 0: attn_impl<0>(b, Qw, Kw, Vt, out, Ks, Vs, Ps); break;
    case 1: attn_impl<1>(b, Qw, Kw, Vt, out, Ks, Vs, Ps); break;
    case 2: attn_impl<2>(b, Qw, Kw, Vt, out, Ks, Vs, Ps); break;
    case 3: attn_impl<3>(b, Qw, Kw, Vt, out, Ks, Vs, Ps); break;
    default: attn_impl<4>(b, Qw, Kw, Vt, out, Ks, Vs, Ps); break;
  }
}

extern "C" void kernel_launch(void* const* d_in, const int* in_sizes, int n_in,
                              void* d_out, int out_size, void* d_ws, size_t ws_size,
                              hipStream_t stream) {
  const float* x  = (const float*)d_in[0];
  const float* Wk = (const float*)d_in[1];
  const float* Wq = (const float*)d_in[2];
  const float* Wv = (const float*)d_in[3];
  float* out = (float*)d_out;

  bf16* Wt = (bf16*)d_ws;
  bf16* Qw = Wt + 3 * 64 * 1024;
  bf16* Kw = Qw + (size_t)81920 * 64;
  bf16* Vt = Kw + (size_t)81920 * 64;

  hipLaunchKernelGGL(wtrans_kernel, dim3(48), dim3(256), 0, stream, Wk, Wq, Wv, Wt);
  hipLaunchKernelGGL(qkv_kernel, dim3(1280), dim3(256), 0, stream, x, Wt, Qw, Kw, Vt);
  // MEASUREMENT ROUND: attn is idempotent (pure function of Qw/Kw/Vt -> out).
  // Launch 5x: attn_time = (dur_us - 119.1) / 4. Deterministic, capture-safe.
  hipLaunchKernelGGL(attn_kernel, dim3(256, 5), dim3(256), 0, stream, Qw, Kw, Vt, out);
  hipLaunchKernelGGL(attn_kernel, dim3(256, 5), dim3(256), 0, stream, Qw, Kw, Vt, out);
  hipLaunchKernelGGL(attn_kernel, dim3(256, 5), dim3(256), 0, stream, Qw, Kw, Vt, out);
  hipLaunchKernelGGL(attn_kernel, dim3(256, 5), dim3(256), 0, stream, Qw, Kw, Vt, out);
  hipLaunchKernelGGL(attn_kernel, dim3(256, 5), dim3(256), 0, stream, Qw, Kw, Vt, out);
}

// Round 9
// 115.813 us; speedup vs baseline: 1.5679x; 1.5679x over previous
//
#include <hip/hip_runtime.h>

typedef __bf16 bf16;
typedef __bf16 bf16x4 __attribute__((ext_vector_type(4)));
typedef __bf16 bf16x8 __attribute__((ext_vector_type(8)));
typedef float f32x4 __attribute__((ext_vector_type(4)));

#define MFMA16(a, b, c) __builtin_amdgcn_mfma_f32_16x16x32_bf16((a), (b), (c), 0, 0, 0)

// global -> LDS DMA, 16B per lane; LDS dest is wave-uniform base + lane*16.
#define GLD16(gp, lp)                                                              \
  __builtin_amdgcn_global_load_lds(                                                \
      (const __attribute__((address_space(1))) unsigned int*)(unsigned long long)(gp), \
      (__attribute__((address_space(3))) unsigned int*)(unsigned long long)(lp), 16, 0, 0)

// B=256, T=320, C=1024, H=64;  M = B*T = 81920
// ws (bf16): Wt [3][64][1024] | Qw [81920][64] | Kw [81920][64] | Vt [256][64][320]

// ---------------- Kernel 0: W -> Wt (bf16, [mat][h][k]) ----------------
__global__ __launch_bounds__(256) void wtrans_kernel(
    const float* __restrict__ Wk, const float* __restrict__ Wq,
    const float* __restrict__ Wv, bf16* __restrict__ Wt) {
  __shared__ bf16 tile[64][65];
  const int mat = blockIdx.x >> 4;
  const int kt = (blockIdx.x & 15) << 6;
  const float* __restrict__ W = (mat == 0) ? Wk : ((mat == 1) ? Wq : Wv);
  const int tid = threadIdx.x;
#pragma unroll
  for (int j = 0; j < 16; ++j) {
    const int i = tid + 256 * j;
    const int k = i >> 6, h = i & 63;
    tile[h][k] = (bf16)W[(kt + k) * 64 + h];
  }
  __syncthreads();
#pragma unroll
  for (int j = 0; j < 16; ++j) {
    const int i = tid + 256 * j;
    const int h = i >> 6, k = i & 63;
    Wt[mat * 65536 + h * 1024 + kt + k] = tile[h][k];
  }
}

// ---------------- Kernel 1: QKV projection, FIFO-clean pipeline ----------------
// 1280 blocks x 4 waves. Wave w owns rows [m0+16w, +16) x ALL 192 cols.
// x: direct per-lane global loads in A-frag layout (registers, depth-2).
// W: block-shared LDS dbuf via global_load_lds (depth-1, L2-resident),
//    read as ds_read_b128 (lgkm counter — decoupled from vmcnt).
// Per-wave VMEM FIFO per step: [wdma(t+1) x6][xload(t+2) x4], so the
// top-of-step vmcnt(4) drains exactly {xload(t+1), wdma(t+1)} and the MFMA
// never waits on a next-tile HBM load (the R5-R8 serialization bug).
__global__ __launch_bounds__(256) void qkv_kernel(
    const float* __restrict__ x, const bf16* __restrict__ Wt,
    bf16* __restrict__ Qw, bf16* __restrict__ Kw, bf16* __restrict__ Vt) {
  __shared__ __align__(16) bf16 Ws[2][192 * 64];  // 48 KB, XOR-swizzled
  const int tid = threadIdx.x;
  const int w = tid >> 6, l = tid & 63;
  const int lr = l & 15, lg = l >> 4;
  const int m0 = blockIdx.x * 64;
  const int r0 = m0 + 16 * w;  // wave's first output row

  f32x4 acc[12];
#pragma unroll
  for (int nf = 0; nf < 12; ++nf) acc[nf] = (f32x4)0.0f;

  // W DMA: instr j covers block-cols 48w+8j..+7; lane l -> col +(l>>3),
  // k-chunk (l&7)*16 B. LDS linear = col*128 + (l&7)*16; source k-byte is
  // XOR'd so (linear dest + swizzled source) == swizzled LDS (rule 21).
  const char* wsrc[6];
#pragma unroll
  for (int j = 0; j < 6; ++j) {
    const int g = 48 * w + 8 * j + (l >> 3);
    wsrc[j] = (const char*)(Wt + (g >> 6) * 65536 + (g & 63) * 1024) +
              (((l & 7) * 16) ^ ((g & 7) << 4));
  }
  auto wdma = [&](int t) {
    char* lb = (char*)&Ws[t & 1][0];
#pragma unroll
    for (int j = 0; j < 6; ++j)
      GLD16(wsrc[j] + t * 128, lb + (48 * w + 8 * j) * 128);
  };

  // x loads directly in A-frag layout: lane holds row r0+lr, f32 k = lg*8..
  const char* xsrc = (const char*)(x + (size_t)(r0 + lr) * 1024) + lg * 32;
  f32x4 gA[4], gB[4];
  auto xload = [&](int t, f32x4* g) {
    const char* p = xsrc + t * 256;
    g[0] = *(const f32x4*)(p);
    g[1] = *(const f32x4*)(p + 16);
    g[2] = *(const f32x4*)(p + 128);
    g[3] = *(const f32x4*)(p + 144);
  };

  wdma(0);
  xload(0, gA);
  xload(1, gB);

  const int sw = (lr & 7) << 4;
  auto step = [&](int t, f32x4* g) {
    if (t < 15) {
      asm volatile("s_waitcnt vmcnt(4)" ::: "memory");
    } else {
      asm volatile("s_waitcnt vmcnt(0)" ::: "memory");
    }
    __builtin_amdgcn_sched_barrier(0);
    __builtin_amdgcn_s_barrier();  // W tile t visible block-wide
    __builtin_amdgcn_sched_barrier(0);

    // convert this tile's x regs to bf16 A-frags (data already waited)
    bf16x8 a0, a1;
#pragma unroll
    for (int i = 0; i < 4; ++i) {
      a0[i] = (bf16)g[0][i]; a0[4 + i] = (bf16)g[1][i];
      a1[i] = (bf16)g[2][i]; a1[4 + i] = (bf16)g[3][i];
    }
    if (t < 15) wdma(t + 1);        // FIFO: older than the x prefetch
    if (t < 14) xload(t + 2, g);    // newest; left in flight by vmcnt(4)

    const char* wb = (const char*)&Ws[t & 1][0];
#pragma unroll
    for (int nf = 0; nf < 12; ++nf) {
      const char* rp = wb + (nf * 16 + lr) * 128;
      const bf16x8 b0 = *(const bf16x8*)(rp + ((lg * 16) ^ sw));
      const bf16x8 b1 = *(const bf16x8*)(rp + ((64 + lg * 16) ^ sw));
      acc[nf] = MFMA16(a0, b0, acc[nf]);
      acc[nf] = MFMA16(a1, b1, acc[nf]);
    }
  };

#pragma unroll
  for (int t2 = 0; t2 < 16; t2 += 2) {
    step(t2, gA);
    step(t2 + 1, gB);
  }

  // epilogue: C[i][j]: i = A-row = lg*4+r (output row r0+i), j = lr (W col)
#pragma unroll
  for (int nf = 0; nf < 12; ++nf) {
    const int mat = nf >> 2;
    const int h = (nf & 3) * 16 + lr;
    const int mb = r0 + lg * 4;  // 16 | r0 and 16 | 320: rows stay in one batch
    if (mat == 2) {  // V transposed [b][h][t], 4 consecutive t = 8B store
      const int bb = mb / 320, tt = mb % 320;
      bf16x4 o;
#pragma unroll
      for (int r = 0; r < 4; ++r) o[r] = (bf16)acc[nf][r];
      *(bf16x4*)(Vt + ((size_t)bb * 64 + h) * 320 + tt) = o;
    } else {
      bf16* __restrict__ dst = (mat == 0) ? Kw : Qw;
#pragma unroll
      for (int r = 0; r < 4; ++r) dst[(size_t)(mb + r) * 64 + h] = (bf16)acc[nf][r];
    }
  }
}

// ---------------- Kernel 2: causal attention (frozen, round-6 version) ----------------
template <int QT>
__device__ __forceinline__ void attn_impl(
    int b, const bf16* __restrict__ Qw, const bf16* __restrict__ Kw,
    const bf16* __restrict__ Vt, float* __restrict__ out,
    char* Ks, char* Vs, char* Ps) {
  constexpr int NT = QT + 1;  // 64-wide s-tiles
  const int tid = threadIdx.x;
  const int w = tid >> 6, l = tid & 63;
  const int lr = l & 15, lg = l >> 4;
  const int t0 = QT * 64 + w * 16;
  const int tq = t0 + lr;

  const bf16* qp = Qw + ((size_t)b * 320 + tq) * 64 + lg * 8;
  const bf16x8 bq0 = *(const bf16x8*)qp;
  const bf16x8 bq1 = *(const bf16x8*)(qp + 32);

  f32x4 acc[NT * 4];
#pragma unroll
  for (int i = 0; i < NT * 4; ++i) acc[i] = (f32x4)0.0f;

  bf16x8 kg0, kg1;
  const int krow = w * 16 + (l >> 2);
  const int kcb = (l & 3) * 16;
  const int ksw = (krow & 7) << 4;
  auto gloadK = [&](int st) {
    const bf16* src = Kw + ((size_t)b * 320 + st * 64 + krow) * 64 + (l & 3) * 8;
    kg0 = *(const bf16x8*)src;
    kg1 = *(const bf16x8*)(src + 32);
  };
  auto dswriteK = [&](int buf) {
    char* base = Ks + buf * 8192 + krow * 128;
    *(bf16x8*)(base + (kcb ^ ksw)) = kg0;
    *(bf16x8*)(base + ((kcb + 64) ^ ksw)) = kg1;
  };

  gloadK(0);
  dswriteK(0);
  asm volatile("s_waitcnt lgkmcnt(0)" ::: "memory");
  __builtin_amdgcn_s_barrier();

  const int asw = (lr & 7) << 4;
#pragma unroll
  for (int st = 0; st < NT; ++st) {
    if (st < QT) gloadK(st + 1);
    const char* kb = Ks + (st & 1) * 8192;
#pragma unroll
    for (int nf = 0; nf < 4; ++nf) {
      const char* rp = kb + (nf * 16 + lr) * 128;
      const bf16x8 a0 = *(const bf16x8*)(rp + ((lg * 16) ^ asw));
      const bf16x8 a1 = *(const bf16x8*)(rp + ((64 + lg * 16) ^ asw));
      acc[st * 4 + nf] = MFMA16(a0, bq0, acc[st * 4 + nf]);
      acc[st * 4 + nf] = MFMA16(a1, bq1, acc[st * 4 + nf]);
    }
    if (st < QT) {
      dswriteK((st + 1) & 1);
      asm volatile("s_waitcnt lgkmcnt(0)" ::: "memory");
      __builtin_amdgcn_s_barrier();
    }
  }

  uint2 vg[4];
  const int vrow = w * 16 + (l >> 4);
  auto gloadV = [&](int st) {
    const bf16* src = Vt + ((size_t)b * 64 + vrow) * 320 + st * 64 + (l & 15) * 4;
#pragma unroll
    for (int i = 0; i < 4; ++i) vg[i] = *(const uint2*)(src + i * 4 * 320);
  };
  auto dswriteV = [&](int buf) {
#pragma unroll
    for (int i = 0; i < 4; ++i) {
      const int hl = vrow + i * 4;
      *(uint2*)(Vs + buf * 8192 + hl * 128 + (((l & 15) * 8) ^ ((hl & 7) << 4))) = vg[i];
    }
  };
  gloadV(0);

  float mx = -1e30f;
#pragma unroll
  for (int st = 0; st < NT; ++st)
#pragma unroll
    for (int nf = 0; nf < 4; ++nf)
#pragma unroll
      for (int r = 0; r < 4; ++r) {
        const int sg = st * 64 + nf * 16 + lg * 4 + r;
        float v = acc[st * 4 + nf][r] * 0.03125f;
        v = (sg > tq) ? -1e30f : v;
        acc[st * 4 + nf][r] = v;
        mx = fmaxf(mx, v);
      }
  mx = fmaxf(mx, __shfl_xor(mx, 16));
  mx = fmaxf(mx, __shfl_xor(mx, 32));
  float sum = 0.f;
#pragma unroll
  for (int i = 0; i < NT * 4; ++i)
#pragma unroll
    for (int r = 0; r < 4; ++r) {
      const float p = __expf(acc[i][r] - mx);
      acc[i][r] = p;
      sum += p;
    }
  sum += __shfl_xor(sum, 16);
  sum += __shfl_xor(sum, 32);
  const float rinv = 1.0f / sum;

  dswriteV(0);
  asm volatile("s_waitcnt lgkmcnt(0)" ::: "memory");
  __builtin_amdgcn_s_barrier();

  char* Pw = Ps + w * 2048;
  f32x4 ao[4];
#pragma unroll
  for (int hf = 0; hf < 4; ++hf) ao[hf] = (f32x4)0.0f;

#pragma unroll
  for (int st = 0; st < NT; ++st) {
    if (st < QT) gloadV(st + 1);
#pragma unroll
    for (int nf = 0; nf < 4; ++nf) {
      bf16x4 o;
#pragma unroll
      for (int r = 0; r < 4; ++r) o[r] = (bf16)(acc[st * 4 + nf][r] * rinv);
      *(bf16x4*)(Pw + lr * 128 + ((nf * 32 + lg * 8) ^ asw)) = o;
    }
    const char* vb = Vs + (st & 1) * 8192;
#pragma unroll
    for (int ks = 0; ks < 2; ++ks) {
      const bf16x8 ap = *(const bf16x8*)(Pw + lr * 128 + ((ks * 64 + lg * 16) ^ asw));
#pragma unroll
      for (int hf = 0; hf < 4; ++hf) {
        const bf16x8 bv =
            *(const bf16x8*)(vb + (hf * 16 + lr) * 128 + ((ks * 64 + lg * 16) ^ asw));
        ao[hf] = MFMA16(ap, bv, ao[hf]);
      }
    }
    if (st < QT) {
      dswriteV((st + 1) & 1);
      asm volatile("s_waitcnt lgkmcnt(0)" ::: "memory");
      __builtin_amdgcn_s_barrier();
    }
  }

  const int rowb = t0 + lg * 4;
#pragma unroll
  for (int hf = 0; hf < 4; ++hf)
#pragma unroll
    for (int r = 0; r < 4; ++r)
      out[((size_t)b * 320 + rowb + r) * 64 + hf * 16 + lr] = ao[hf][r];
}

__global__ __launch_bounds__(256) void attn_kernel(
    const bf16* __restrict__ Qw, const bf16* __restrict__ Kw,
    const bf16* __restrict__ Vt, float* __restrict__ out) {
  __shared__ __align__(16) char Ks[2 * 8192];
  __shared__ __align__(16) char Vs[2 * 8192];
  __shared__ __align__(16) char Ps[4 * 2048];
  const int b = blockIdx.x;
  const int qt = 4 - blockIdx.y;  // heavy blocks dispatch first
  switch (qt) {
    case 0: attn_impl<0>(b, Qw, Kw, Vt, out, Ks, Vs, Ps); break;
    case 1: attn_impl<1>(b, Qw, Kw, Vt, out, Ks, Vs, Ps); break;
    case 2: attn_impl<2>(b, Qw, Kw, Vt, out, Ks, Vs, Ps); break;
    case 3: attn_impl<3>(b, Qw, Kw, Vt, out, Ks, Vs, Ps); break;
    default: attn_impl<4>(b, Qw, Kw, Vt, out, Ks, Vs, Ps); break;
  }
}

extern "C" void kernel_launch(void* const* d_in, const int* in_sizes, int n_in,
                              void* d_out, int out_size, void* d_ws, size_t ws_size,
                              hipStream_t stream) {
  const float* x  = (const float*)d_in[0];
  const float* Wk = (const float*)d_in[1];
  const float* Wq = (const float*)d_in[2];
  const float* Wv = (const float*)d_in[3];
  float* out = (float*)d_out;

  bf16* Wt = (bf16*)d_ws;
  bf16* Qw = Wt + 3 * 64 * 1024;
  bf16* Kw = Qw + (size_t)81920 * 64;
  bf16* Vt = Kw + (size_t)81920 * 64;

  hipLaunchKernelGGL(wtrans_kernel, dim3(48), dim3(256), 0, stream, Wk, Wq, Wv, Wt);
  hipLaunchKernelGGL(qkv_kernel, dim3(1280), dim3(256), 0, stream, x, Wt, Qw, Kw, Vt);
  hipLaunchKernelGGL(attn_kernel, dim3(256, 5), dim3(256), 0, stream, Qw, Kw, Vt, out);
}

// Round 10
// 112.572 us; speedup vs baseline: 1.6130x; 1.0288x over previous
//
#include <hip/hip_runtime.h>

typedef __bf16 bf16;
typedef __bf16 bf16x4 __attribute__((ext_vector_type(4)));
typedef __bf16 bf16x8 __attribute__((ext_vector_type(8)));
typedef float f32x4 __attribute__((ext_vector_type(4)));

#define MFMA16(a, b, c) __builtin_amdgcn_mfma_f32_16x16x32_bf16((a), (b), (c), 0, 0, 0)

// global -> LDS DMA, 16B per lane; LDS dest is wave-uniform base + lane*16.
#define GLD16(gp, lp)                                                              \
  __builtin_amdgcn_global_load_lds(                                                \
      (const __attribute__((address_space(1))) unsigned int*)(unsigned long long)(gp), \
      (__attribute__((address_space(3))) unsigned int*)(unsigned long long)(lp), 16, 0, 0)

// B=256, T=320, C=1024, H=64;  M = B*T = 81920
// ws (bf16): Wt [3][64][1024] | Qw [81920][64] | Kw [81920][64] | Vt [256][64][320]

// ---------------- Kernel 0: W -> Wt (bf16, [mat][h][k]) ----------------
__global__ __launch_bounds__(256) void wtrans_kernel(
    const float* __restrict__ Wk, const float* __restrict__ Wq,
    const float* __restrict__ Wv, bf16* __restrict__ Wt) {
  __shared__ bf16 tile[64][65];
  const int mat = blockIdx.x >> 4;
  const int kt = (blockIdx.x & 15) << 6;
  const float* __restrict__ W = (mat == 0) ? Wk : ((mat == 1) ? Wq : Wv);
  const int tid = threadIdx.x;
#pragma unroll
  for (int j = 0; j < 16; ++j) {
    const int i = tid + 256 * j;
    const int k = i >> 6, h = i & 63;
    tile[h][k] = (bf16)W[(kt + k) * 64 + h];
  }
  __syncthreads();
#pragma unroll
  for (int j = 0; j < 16; ++j) {
    const int i = tid + 256 * j;
    const int h = i >> 6, k = i & 63;
    Wt[mat * 65536 + h * 1024 + kt + k] = tile[h][k];
  }
}

// ---------------- Kernel 1: QKV projection, FIFO-clean + coalesced epilogue ----------------
// Main loop identical to round 9. NEW: C staged through LDS transposed
// (Cs_T[192][72] bf16 over the Ws area) -> K/Q/V written as 32 B/lane,
// 2 KB/wave contiguous stores (kills the V 8x / KQ 2x write amplification).
__global__ __launch_bounds__(256) void qkv_kernel(
    const float* __restrict__ x, const bf16* __restrict__ Wt,
    bf16* __restrict__ Qw, bf16* __restrict__ Kw, bf16* __restrict__ Vt) {
  __shared__ __align__(16) bf16 Ws[2][192 * 64];  // 48 KB, XOR-swizzled
  const int tid = threadIdx.x;
  const int w = tid >> 6, l = tid & 63;
  const int lr = l & 15, lg = l >> 4;
  const int m0 = blockIdx.x * 64;
  const int r0 = m0 + 16 * w;  // wave's first output row

  f32x4 acc[12];
#pragma unroll
  for (int nf = 0; nf < 12; ++nf) acc[nf] = (f32x4)0.0f;

  // W DMA: instr j covers block-cols 48w+8j..+7; lane l -> col +(l>>3),
  // k-chunk (l&7)*16 B. Linear LDS dest + XOR'd source byte (rule 21).
  const char* wsrc[6];
#pragma unroll
  for (int j = 0; j < 6; ++j) {
    const int g = 48 * w + 8 * j + (l >> 3);
    wsrc[j] = (const char*)(Wt + (g >> 6) * 65536 + (g & 63) * 1024) +
              (((l & 7) * 16) ^ ((g & 7) << 4));
  }
  auto wdma = [&](int t) {
    char* lb = (char*)&Ws[t & 1][0];
#pragma unroll
    for (int j = 0; j < 6; ++j)
      GLD16(wsrc[j] + t * 128, lb + (48 * w + 8 * j) * 128);
  };

  // x loads directly in A-frag layout: lane holds row r0+lr, f32 k = lg*8..
  const char* xsrc = (const char*)(x + (size_t)(r0 + lr) * 1024) + lg * 32;
  f32x4 gA[4], gB[4];
  auto xload = [&](int t, f32x4* g) {
    const char* p = xsrc + t * 256;
    g[0] = *(const f32x4*)(p);
    g[1] = *(const f32x4*)(p + 16);
    g[2] = *(const f32x4*)(p + 128);
    g[3] = *(const f32x4*)(p + 144);
  };

  wdma(0);
  xload(0, gA);
  xload(1, gB);

  const int sw = (lr & 7) << 4;
  auto step = [&](int t, f32x4* g) {
    if (t < 15) {
      asm volatile("s_waitcnt vmcnt(4)" ::: "memory");
    } else {
      asm volatile("s_waitcnt vmcnt(0)" ::: "memory");
    }
    __builtin_amdgcn_sched_barrier(0);
    __builtin_amdgcn_s_barrier();  // W tile t visible block-wide
    __builtin_amdgcn_sched_barrier(0);

    bf16x8 a0, a1;
#pragma unroll
    for (int i = 0; i < 4; ++i) {
      a0[i] = (bf16)g[0][i]; a0[4 + i] = (bf16)g[1][i];
      a1[i] = (bf16)g[2][i]; a1[4 + i] = (bf16)g[3][i];
    }
    if (t < 15) wdma(t + 1);        // FIFO: older than the x prefetch
    if (t < 14) xload(t + 2, g);    // newest; left in flight by vmcnt(4)

    const char* wb = (const char*)&Ws[t & 1][0];
#pragma unroll
    for (int nf = 0; nf < 12; ++nf) {
      const char* rp = wb + (nf * 16 + lr) * 128;
      const bf16x8 b0 = *(const bf16x8*)(rp + ((lg * 16) ^ sw));
      const bf16x8 b1 = *(const bf16x8*)(rp + ((64 + lg * 16) ^ sw));
      acc[nf] = MFMA16(a0, b0, acc[nf]);
      acc[nf] = MFMA16(a1, b1, acc[nf]);
    }
  };

#pragma unroll
  for (int t2 = 0; t2 < 16; t2 += 2) {
    step(t2, gA);
    step(t2 + 1, gB);
  }

  // ---- epilogue: C -> LDS transposed -> coalesced global writes ----
  // Cs_T[j:192][i:64 + 8 pad] bf16 (27.6 KB) reuses the Ws area.
  {
    bf16* Cs = &Ws[0][0];
    asm volatile("s_waitcnt lgkmcnt(0)" ::: "memory");
    __builtin_amdgcn_sched_barrier(0);
    __builtin_amdgcn_s_barrier();  // all waves done reading Ws
    __builtin_amdgcn_sched_barrier(0);
    // C[i][j]: i = 16w + lg*4 + r, j = nf*16 + lr  -> Cs[j][i], b64 packed over r
#pragma unroll
    for (int nf = 0; nf < 12; ++nf) {
      bf16x4 o;
#pragma unroll
      for (int r = 0; r < 4; ++r) o[r] = (bf16)acc[nf][r];
      *(bf16x4*)(Cs + (nf * 16 + lr) * 72 + 16 * w + lg * 4) = o;
    }
    asm volatile("s_waitcnt lgkmcnt(0)" ::: "memory");
    __builtin_amdgcn_sched_barrier(0);
    __builtin_amdgcn_s_barrier();  // Cs complete
    __builtin_amdgcn_sched_barrier(0);

    const int i = tid >> 2;  // output row (K/Q) or h (V), 0..63
    const int c = tid & 3;   // 32 B chunk
    const int bb = m0 / 320, tt0 = m0 % 320;  // 64 | 320: block in one batch
    // K, Q: gather 16 column scalars each (epilogue-once; conflicts ok)
    bf16x8 kk0, kk1, qq0, qq1;
#pragma unroll
    for (int s = 0; s < 8; ++s) {
      kk0[s] = Cs[(c * 16 + s) * 72 + i];
      kk1[s] = Cs[(c * 16 + 8 + s) * 72 + i];
      qq0[s] = Cs[(64 + c * 16 + s) * 72 + i];
      qq1[s] = Cs[(64 + c * 16 + 8 + s) * 72 + i];
    }
    *(bf16x8*)(Kw + (size_t)(m0 + i) * 64 + c * 16) = kk0;
    *(bf16x8*)(Kw + (size_t)(m0 + i) * 64 + c * 16 + 8) = kk1;
    *(bf16x8*)(Qw + (size_t)(m0 + i) * 64 + c * 16) = qq0;
    *(bf16x8*)(Qw + (size_t)(m0 + i) * 64 + c * 16 + 8) = qq1;
    // V[h=i][t-chunk]: contiguous in Cs_T (col 128+h), 2 x b128
    const bf16x8 v0 = *(const bf16x8*)(Cs + (128 + i) * 72 + c * 16);
    const bf16x8 v1 = *(const bf16x8*)(Cs + (128 + i) * 72 + c * 16 + 8);
    *(bf16x8*)(Vt + ((size_t)bb * 64 + i) * 320 + tt0 + c * 16) = v0;
    *(bf16x8*)(Vt + ((size_t)bb * 64 + i) * 320 + tt0 + c * 16 + 8) = v1;
  }
}

// ---------------- Kernel 2: causal attention (frozen, round-6 version) ----------------
template <int QT>
__device__ __forceinline__ void attn_impl(
    int b, const bf16* __restrict__ Qw, const bf16* __restrict__ Kw,
    const bf16* __restrict__ Vt, float* __restrict__ out,
    char* Ks, char* Vs, char* Ps) {
  constexpr int NT = QT + 1;  // 64-wide s-tiles
  const int tid = threadIdx.x;
  const int w = tid >> 6, l = tid & 63;
  const int lr = l & 15, lg = l >> 4;
  const int t0 = QT * 64 + w * 16;
  const int tq = t0 + lr;

  const bf16* qp = Qw + ((size_t)b * 320 + tq) * 64 + lg * 8;
  const bf16x8 bq0 = *(const bf16x8*)qp;
  const bf16x8 bq1 = *(const bf16x8*)(qp + 32);

  f32x4 acc[NT * 4];
#pragma unroll
  for (int i = 0; i < NT * 4; ++i) acc[i] = (f32x4)0.0f;

  bf16x8 kg0, kg1;
  const int krow = w * 16 + (l >> 2);
  const int kcb = (l & 3) * 16;
  const int ksw = (krow & 7) << 4;
  auto gloadK = [&](int st) {
    const bf16* src = Kw + ((size_t)b * 320 + st * 64 + krow) * 64 + (l & 3) * 8;
    kg0 = *(const bf16x8*)src;
    kg1 = *(const bf16x8*)(src + 32);
  };
  auto dswriteK = [&](int buf) {
    char* base = Ks + buf * 8192 + krow * 128;
    *(bf16x8*)(base + (kcb ^ ksw)) = kg0;
    *(bf16x8*)(base + ((kcb + 64) ^ ksw)) = kg1;
  };

  gloadK(0);
  dswriteK(0);
  asm volatile("s_waitcnt lgkmcnt(0)" ::: "memory");
  __builtin_amdgcn_s_barrier();

  const int asw = (lr & 7) << 4;
#pragma unroll
  for (int st = 0; st < NT; ++st) {
    if (st < QT) gloadK(st + 1);
    const char* kb = Ks + (st & 1) * 8192;
#pragma unroll
    for (int nf = 0; nf < 4; ++nf) {
      const char* rp = kb + (nf * 16 + lr) * 128;
      const bf16x8 a0 = *(const bf16x8*)(rp + ((lg * 16) ^ asw));
      const bf16x8 a1 = *(const bf16x8*)(rp + ((64 + lg * 16) ^ asw));
      acc[st * 4 + nf] = MFMA16(a0, bq0, acc[st * 4 + nf]);
      acc[st * 4 + nf] = MFMA16(a1, bq1, acc[st * 4 + nf]);
    }
    if (st < QT) {
      dswriteK((st + 1) & 1);
      asm volatile("s_waitcnt lgkmcnt(0)" ::: "memory");
      __builtin_amdgcn_s_barrier();
    }
  }

  uint2 vg[4];
  const int vrow = w * 16 + (l >> 4);
  auto gloadV = [&](int st) {
    const bf16* src = Vt + ((size_t)b * 64 + vrow) * 320 + st * 64 + (l & 15) * 4;
#pragma unroll
    for (int i = 0; i < 4; ++i) vg[i] = *(const uint2*)(src + i * 4 * 320);
  };
  auto dswriteV = [&](int buf) {
#pragma unroll
    for (int i = 0; i < 4; ++i) {
      const int hl = vrow + i * 4;
      *(uint2*)(Vs + buf * 8192 + hl * 128 + (((l & 15) * 8) ^ ((hl & 7) << 4))) = vg[i];
    }
  };
  gloadV(0);

  float mx = -1e30f;
#pragma unroll
  for (int st = 0; st < NT; ++st)
#pragma unroll
    for (int nf = 0; nf < 4; ++nf)
#pragma unroll
      for (int r = 0; r < 4; ++r) {
        const int sg = st * 64 + nf * 16 + lg * 4 + r;
        float v = acc[st * 4 + nf][r] * 0.03125f;
        v = (sg > tq) ? -1e30f : v;
        acc[st * 4 + nf][r] = v;
        mx = fmaxf(mx, v);
      }
  mx = fmaxf(mx, __shfl_xor(mx, 16));
  mx = fmaxf(mx, __shfl_xor(mx, 32));
  float sum = 0.f;
#pragma unroll
  for (int i = 0; i < NT * 4; ++i)
#pragma unroll
    for (int r = 0; r < 4; ++r) {
      const float p = __expf(acc[i][r] - mx);
      acc[i][r] = p;
      sum += p;
    }
  sum += __shfl_xor(sum, 16);
  sum += __shfl_xor(sum, 32);
  const float rinv = 1.0f / sum;

  dswriteV(0);
  asm volatile("s_waitcnt lgkmcnt(0)" ::: "memory");
  __builtin_amdgcn_s_barrier();

  char* Pw = Ps + w * 2048;
  f32x4 ao[4];
#pragma unroll
  for (int hf = 0; hf < 4; ++hf) ao[hf] = (f32x4)0.0f;

#pragma unroll
  for (int st = 0; st < NT; ++st) {
    if (st < QT) gloadV(st + 1);
#pragma unroll
    for (int nf = 0; nf < 4; ++nf) {
      bf16x4 o;
#pragma unroll
      for (int r = 0; r < 4; ++r) o[r] = (bf16)(acc[st * 4 + nf][r] * rinv);
      *(bf16x4*)(Pw + lr * 128 + ((nf * 32 + lg * 8) ^ asw)) = o;
    }
    const char* vb = Vs + (st & 1) * 8192;
#pragma unroll
    for (int ks = 0; ks < 2; ++ks) {
      const bf16x8 ap = *(const bf16x8*)(Pw + lr * 128 + ((ks * 64 + lg * 16) ^ asw));
#pragma unroll
      for (int hf = 0; hf < 4; ++hf) {
        const bf16x8 bv =
            *(const bf16x8*)(vb + (hf * 16 + lr) * 128 + ((ks * 64 + lg * 16) ^ asw));
        ao[hf] = MFMA16(ap, bv, ao[hf]);
      }
    }
    if (st < QT) {
      dswriteV((st + 1) & 1);
      asm volatile("s_waitcnt lgkmcnt(0)" ::: "memory");
      __builtin_amdgcn_s_barrier();
    }
  }

  const int rowb = t0 + lg * 4;
#pragma unroll
  for (int hf = 0; hf < 4; ++hf)
#pragma unroll
    for (int r = 0; r < 4; ++r)
      out[((size_t)b * 320 + rowb + r) * 64 + hf * 16 + lr] = ao[hf][r];
}

__global__ __launch_bounds__(256) void attn_kernel(
    const bf16* __restrict__ Qw, const bf16* __restrict__ Kw,
    const bf16* __restrict__ Vt, float* __restrict__ out) {
  __shared__ __align__(16) char Ks[2 * 8192];
  __shared__ __align__(16) char Vs[2 * 8192];
  __shared__ __align__(16) char Ps[4 * 2048];
  const int b = blockIdx.x;
  const int qt = 4 - blockIdx.y;  // heavy blocks dispatch first
  switch (qt) {
    case 0: attn_impl<0>(b, Qw, Kw, Vt, out, Ks, Vs, Ps); break;
    case 1: attn_impl<1>(b, Qw, Kw, Vt, out, Ks, Vs, Ps); break;
    case 2: attn_impl<2>(b, Qw, Kw, Vt, out, Ks, Vs, Ps); break;
    case 3: attn_impl<3>(b, Qw, Kw, Vt, out, Ks, Vs, Ps); break;
    default: attn_impl<4>(b, Qw, Kw, Vt, out, Ks, Vs, Ps); break;
  }
}

extern "C" void kernel_launch(void* const* d_in, const int* in_sizes, int n_in,
                              void* d_out, int out_size, void* d_ws, size_t ws_size,
                              hipStream_t stream) {
  const float* x  = (const float*)d_in[0];
  const float* Wk = (const float*)d_in[1];
  const float* Wq = (const float*)d_in[2];
  const float* Wv = (const float*)d_in[3];
  float* out = (float*)d_out;

  bf16* Wt = (bf16*)d_ws;
  bf16* Qw = Wt + 3 * 64 * 1024;
  bf16* Kw = Qw + (size_t)81920 * 64;
  bf16* Vt = Kw + (size_t)81920 * 64;

  hipLaunchKernelGGL(wtrans_kernel, dim3(48), dim3(256), 0, stream, Wk, Wq, Wv, Wt);
  hipLaunchKernelGGL(qkv_kernel, dim3(1280), dim3(256), 0, stream, x, Wt, Qw, Kw, Vt);
  hipLaunchKernelGGL(attn_kernel, dim3(256, 5), dim3(256), 0, stream, Qw, Kw, Vt, out);
}